// Round 14
// baseline (181.173 us; speedup 1.0000x reference)
//
#include <hip/hip_runtime.h>

typedef unsigned short ushort_t;
typedef __attribute__((ext_vector_type(8))) short short8;   // 8 bf16 (4 VGPRs)
typedef __attribute__((ext_vector_type(4))) short short4v;  // 4 bf16 (8 B)
typedef __attribute__((ext_vector_type(4))) float floatx4;  // 4 fp32 acc
typedef __attribute__((ext_vector_type(4))) unsigned uint4v;

#define DEV static __device__ __forceinline__
#define NEG_BIG (-1e30f)

typedef const __attribute__((address_space(1))) unsigned int* gas_ptr;
typedef __attribute__((address_space(3))) unsigned int* las_ptr;

// async global->LDS, 16B per lane; LDS dest = base + lane*16 (wave-uniform base)
DEV void async16(const ushort_t* g, ushort_t* l) {
    __builtin_amdgcn_global_load_lds((gas_ptr)(const void*)g, (las_ptr)(void*)l, 16, 0, 0);
}

// raw v_exp_f32: 2^x in ONE trans op (libm exp2f = ~10-op OCML path, R23;
// __expf = mul+exp, R19). Input pre-scaled by log2(e) in gemm_qkv.
DEV float ex2(float x) {
    float r;
    asm("v_exp_f32 %0, %1" : "=v"(r) : "v"(x));
    return r;
}

DEV float bf2f(ushort_t u) {
    union { unsigned u; float f; } v; v.u = ((unsigned)u) << 16; return v.f;
}
DEV ushort_t f2bf(float f) {            // RNE — for values feeding long chains
    union { float f; unsigned u; } v; v.f = f;
    unsigned r = v.u + 0x7FFF + ((v.u >> 16) & 1);
    return (ushort_t)(r >> 16);
}
DEV ushort_t f2bf_trunc(float f) {      // 1-op truncation — P / O only (R13)
    union { float f; unsigned u; } v; v.f = f;
    return (ushort_t)(v.u >> 16);
}
DEV float scrub_f32_bits(unsigned u) {  // inf/nan -> 0
    if (((u >> 23) & 0xFF) == 0xFF) u = 0;
    union { unsigned u; float f; } v; v.u = u; return v.f;
}
DEV float scrub_bf16_bits(ushort_t u) {
    if (((u >> 7) & 0xFF) == 0xFF) u = 0;
    return bf2f(u);
}

// Probe: fp32 vs bf16 raw data (proven in R3/R4). Block-uniform result.
DEV int probe_is_f32(const ushort_t* __restrict__ p) {
    int tid = threadIdx.x + threadIdx.y * blockDim.x;
    int nthr = blockDim.x * blockDim.y;
    __shared__ int cnt;
    if (tid == 0) cnt = 0;
    __syncthreads();
    int weird = 0;
    for (int i = tid; i < 2048; i += nthr) {
        unsigned e = (p[i] >> 7) & 0xFF;
        weird += (e >= 0x90) ? 1 : 0;
    }
#pragma unroll
    for (int off = 32; off; off >>= 1) weird += __shfl_xor(weird, off);
    if ((tid & 63) == 0) atomicAdd(&cnt, weird);
    __syncthreads();
    return cnt > 16;
}

// ----------------------------------------------- fused prep (1 launch) ------
// R26 (verified): G13-vectorized transpose + RMSNorm. Per-element arithmetic
// identical to scalar version (same scrub, same f2bf RNE).
__global__ void prep_kernel(const ushort_t* __restrict__ W0,
                            const ushort_t* __restrict__ W1,
                            const ushort_t* __restrict__ W2,
                            const ushort_t* __restrict__ W3,
                            ushort_t* __restrict__ WTq3,
                            ushort_t* __restrict__ WoT,
                            const ushort_t* __restrict__ x,
                            const ushort_t* __restrict__ g,
                            ushort_t* __restrict__ xn) {
    int is_f32 = probe_is_f32(x);
    int z = blockIdx.z;
    int tid = threadIdx.y * 32 + threadIdx.x;
    if (z < 4) {
        const ushort_t* W = (z == 0) ? W0 : (z == 1) ? W1 : (z == 2) ? W2 : W3;
        __shared__ ushort_t tile[32][36];   // row stride 36 shorts = 72 B
        int kk = tid >> 3;                  // 0..31  (k-local)
        int nl = (tid & 7) * 4;             // 0,4,..,28 (n-local)
        size_t src = (size_t)(blockIdx.y * 32 + kk) * 1024 + blockIdx.x * 32 + nl;
        short4v tv;
        if (is_f32) {
            uint4v u = *(const uint4v*)((const unsigned*)W + src);
#pragma unroll
            for (int i = 0; i < 4; i++) tv[i] = (short)f2bf(scrub_f32_bits(u[i]));
        } else {
            short4v u = *(const short4v*)(W + src);
#pragma unroll
            for (int i = 0; i < 4; i++) tv[i] = (short)f2bf(scrub_bf16_bits((ushort_t)u[i]));
        }
        *(short4v*)(&tile[kk][nl]) = tv;
        __syncthreads();
        int nn = tid >> 3;                  // n-local
        int kl = (tid & 7) * 4;             // k-local
        ushort_t* dst = (z < 3) ? WTq3 : WoT;
        int ny = blockIdx.x * 32 + ((z < 3) ? z * 1024 : 0) + nn;
        short4v ov;
#pragma unroll
        for (int i = 0; i < 4; i++) ov[i] = tile[kl + i][nn];
        *(short4v*)(dst + (size_t)ny * 1024 + blockIdx.y * 32 + kl) = ov;
    } else {
        int row = (z - 4) * 1024 + blockIdx.y * 32 + blockIdx.x;
        float vals[4], gv[4];
        size_t base = (size_t)row * 1024 + tid * 4;
        if (is_f32) {
            uint4v xv = *(const uint4v*)((const unsigned*)x + base);
            uint4v gvv = *(const uint4v*)((const unsigned*)g + tid * 4);
#pragma unroll
            for (int i = 0; i < 4; i++) {
                vals[i] = scrub_f32_bits(xv[i]);
                gv[i]   = scrub_f32_bits(gvv[i]);
            }
        } else {
            short4v xv = *(const short4v*)(x + base);
            short4v gvv = *(const short4v*)(g + tid * 4);
#pragma unroll
            for (int i = 0; i < 4; i++) {
                vals[i] = scrub_bf16_bits((ushort_t)xv[i]);
                gv[i]   = scrub_bf16_bits((ushort_t)gvv[i]);
            }
        }
        float ss = vals[0]*vals[0] + vals[1]*vals[1] + vals[2]*vals[2] + vals[3]*vals[3];
#pragma unroll
        for (int off = 32; off > 0; off >>= 1) ss += __shfl_xor(ss, off);
        __shared__ float red[4];
        if ((tid & 63) == 0) red[tid >> 6] = ss;
        __syncthreads();
        ss = red[0] + red[1] + red[2] + red[3];
        float inv = rsqrtf(ss * (1.0f / 1024.0f) + 1e-6f);
        short4v ov;
#pragma unroll
        for (int i = 0; i < 4; i++) ov[i] = (short)f2bf(vals[i] * inv * gv[i]);
        *(short4v*)(xn + base) = ov;
    }
}

// ------------------------------------------------------- fused QKV GEMM ----
// 128x128 tile, BK=64, COALESCED async staging (R8/R10-verified; R9 proved
// bank conflicts benign / coalescing binding). XCD-region swizzle.
// Epilogue: fast-math RoPE (__sinf/__cosf), packed V scatter.
// q pre-scale = 0.125 * log2(e): attn softmax uses raw v_exp_f32 (2^x).
__global__ __launch_bounds__(256, 4) void gemm_qkv(const ushort_t* __restrict__ A,
                                                   const ushort_t* __restrict__ Bt,
                                                   ushort_t* __restrict__ qb,
                                                   ushort_t* __restrict__ kb,
                                                   ushort_t* __restrict__ vt) {
    const int K = 1024;
    int tid = threadIdx.x;
    int lane = tid & 63, w = tid >> 6;
    int c = lane & 15, quad = lane >> 4;
    int mh = w >> 1, nh = w & 1;
    int lin = blockIdx.y * gridDim.x + blockIdx.x;     // 768 blocks
    int xcd = lin & 7, idx = lin >> 3;
    int bm = ((xcd & 3) * 8 + (idx & 7)) * 128;        // m-block in [0,32)
    int bn = ((xcd >> 2) * 12 + (idx >> 3)) * 128;     // n-block in [0,24)
    int lr = lane >> 2, lq = lane & 3;                 // staging lane map

    __shared__ __align__(16) ushort_t As[16 * 512];    // 16 KB
    __shared__ __align__(16) ushort_t Bs[16 * 512];    // 16 KB

    const floatx4 zero = {0.f, 0.f, 0.f, 0.f};
    floatx4 acc[4][4];
#pragma unroll
    for (int i = 0; i < 4; i++)
#pragma unroll
        for (int j = 0; j < 4; j++) acc[i][j] = zero;

    for (int k0 = 0; k0 < K; k0 += 64) {
        __syncthreads();
#pragma unroll
        for (int ci = 0; ci < 8; ci++) {
            int ch = w * 8 + ci;              // 0..31, wave-uniform
            if (ch < 16) {
                int rg = ch >> 1, kc = ch & 1;
                async16(A + (size_t)(bm + rg * 16 + lr) * K + k0 + kc * 32 + lq * 8,
                        As + ch * 512);
            } else {
                int b2 = ch - 16;
                int rg = b2 >> 1, kc = b2 & 1;
                async16(Bt + (size_t)(bn + rg * 16 + lr) * K + k0 + kc * 32 + lq * 8,
                        Bs + b2 * 512);
            }
        }
        __syncthreads();
#pragma unroll
        for (int kc = 0; kc < 2; kc++) {
            short8 af[4], bf[4];
#pragma unroll
            for (int i = 0; i < 4; i++)
                af[i] = *(const short8*)(As + ((mh * 4 + i) * 2 + kc) * 512 + c * 32 + quad * 8);
#pragma unroll
            for (int j = 0; j < 4; j++)
                bf[j] = *(const short8*)(Bs + ((nh * 4 + j) * 2 + kc) * 512 + c * 32 + quad * 8);
#pragma unroll
            for (int i = 0; i < 4; i++)
#pragma unroll
                for (int j = 0; j < 4; j++)
                    acc[i][j] = __builtin_amdgcn_mfma_f32_16x16x32_bf16(af[i], bf[j], acc[i][j], 0, 0, 0);
        }
    }

    int proj = bn >> 10;                 // 0=q, 1=k, 2=v (blocks never straddle)
    int n0 = (bn & 1023) + nh * 64;
    if (proj < 2) {                      // RoPE: d = j*16+c, pairs (j, j+2)
        float th0 = exp2f((float)c * (-19.931568569324174f / 32.0f));
        float th1 = exp2f((float)(16 + c) * (-19.931568569324174f / 32.0f));
        // q scale folds 1/sqrt(dh)=0.125 AND log2(e) so attn uses exp2 directly
        float scale = (proj == 0) ? 0.125f * 1.4426950408889634f : 1.0f;
#pragma unroll
        for (int i = 0; i < 4; i++)
#pragma unroll
            for (int r = 0; r < 4; r++) {
                int s = (bm + mh * 64 + i * 16 + quad * 4 + r) & 2047;
                float a0 = (float)s * th0, a1 = (float)s * th1;
                float sn0 = __sinf(a0), cs0 = __cosf(a0);
                float sn1 = __sinf(a1), cs1 = __cosf(a1);
                float x1a = acc[i][0][r], x2a = acc[i][2][r];
                acc[i][0][r] = (x1a * cs0 - x2a * sn0) * scale;
                acc[i][2][r] = (x1a * sn0 + x2a * cs0) * scale;
                float x1b = acc[i][1][r], x2b = acc[i][3][r];
                acc[i][1][r] = (x1b * cs1 - x2b * sn1) * scale;
                acc[i][3][r] = (x1b * sn1 + x2b * cs1) * scale;
            }
        ushort_t* dst = (proj == 0) ? qb : kb;
#pragma unroll
        for (int i = 0; i < 4; i++)
#pragma unroll
            for (int j = 0; j < 4; j++)
#pragma unroll
                for (int r = 0; r < 4; r++) {
                    int row = bm + mh * 64 + i * 16 + quad * 4 + r;
                    dst[(size_t)row * 1024 + n0 + j * 16 + c] = f2bf(acc[i][j][r]);
                }
    } else {                             // V: packed 8-B scatter (4 consecutive s)
#pragma unroll
        for (int i = 0; i < 4; i++) {
            int row0 = bm + mh * 64 + i * 16 + quad * 4;
            int b = row0 >> 11, s0v = row0 & 2047;
#pragma unroll
            for (int j = 0; j < 4; j++) {
                int col = n0 + j * 16 + c;
                int hh = col >> 6, dh = col & 63;
                short4v pk;
#pragma unroll
                for (int r = 0; r < 4; r++) pk[r] = (short)f2bf(acc[i][j][r]);
                *(short4v*)(vt + (size_t)((b * 16 + hh) * 64 + dh) * 2048 + s0v) = pk;
            }
        }
    }
}

// ----------------------------------------------------- output projection ---
__global__ __launch_bounds__(256, 4) void gemm_out(const ushort_t* __restrict__ A,
                                                   const ushort_t* __restrict__ Bt,
                                                   float* __restrict__ C) {
    const int K = 1024, N = 1024;
    int tid = threadIdx.x;
    int lane = tid & 63, w = tid >> 6;
    int c = lane & 15, quad = lane >> 4;
    int mh = w >> 1, nh = w & 1;
    int lin = blockIdx.y * gridDim.x + blockIdx.x;     // 512 blocks
    int xcd = lin & 7, idx = lin >> 3;
    int bm = ((xcd & 3) * 8 + (idx & 7)) * 128;
    int bn = ((xcd >> 2) * 8 + (idx >> 3)) * 64;
    int lr = lane >> 2, lq = lane & 3;

    __shared__ __align__(16) ushort_t As[16 * 512];
    __shared__ __align__(16) ushort_t Bs[8 * 512];

    const floatx4 zero = {0.f, 0.f, 0.f, 0.f};
    floatx4 acc[4][2];
#pragma unroll
    for (int i = 0; i < 4; i++)
#pragma unroll
        for (int j = 0; j < 2; j++) acc[i][j] = zero;

    for (int k0 = 0; k0 < K; k0 += 64) {
        __syncthreads();
#pragma unroll
        for (int ci = 0; ci < 6; ci++) {
            int ch = w * 6 + ci;              // 0..23, wave-uniform
            if (ch < 16) {
                int rg = ch >> 1, kc = ch & 1;
                async16(A + (size_t)(bm + rg * 16 + lr) * K + k0 + kc * 32 + lq * 8,
                        As + ch * 512);
            } else {
                int b2 = ch - 16;
                int rg = b2 >> 1, kc = b2 & 1;
                async16(Bt + (size_t)(bn + rg * 16 + lr) * K + k0 + kc * 32 + lq * 8,
                        Bs + b2 * 512);
            }
        }
        __syncthreads();
#pragma unroll
        for (int kc = 0; kc < 2; kc++) {
            short8 af[4], bf[2];
#pragma unroll
            for (int i = 0; i < 4; i++)
                af[i] = *(const short8*)(As + ((mh * 4 + i) * 2 + kc) * 512 + c * 32 + quad * 8);
#pragma unroll
            for (int j = 0; j < 2; j++)
                bf[j] = *(const short8*)(Bs + ((nh * 2 + j) * 2 + kc) * 512 + c * 32 + quad * 8);
#pragma unroll
            for (int i = 0; i < 4; i++)
#pragma unroll
                for (int j = 0; j < 2; j++)
                    acc[i][j] = __builtin_amdgcn_mfma_f32_16x16x32_bf16(af[i], bf[j], acc[i][j], 0, 0, 0);
        }
    }
#pragma unroll
    for (int i = 0; i < 4; i++)
#pragma unroll
        for (int j = 0; j < 2; j++)
#pragma unroll
            for (int r = 0; r < 4; r++) {
                int row = bm + mh * 64 + i * 16 + quad * 4 + r;
                int col = bn + nh * 32 + j * 16 + c;
                C[(size_t)row * N + col] = acc[i][j][r];
            }
}

// -------------------------------------------------------------- attention ---
// R27 = R25 per-tile code, wrapped in a 2-subproblem loop: block y handles
// q-tiles (31-y) then y -> EVERY block = (32-y)+(y+1) = 33 tiles exactly.
// Model-free load balance: 512 blocks = exactly 2/CU, identical work, so
// per-CU totals are equal under ANY dispatch rule (R20's remap depended on
// a round-robin model and was null; this closes the imbalance question).
// One extra __syncthreads between subproblems protects Ks/Vs reuse (a fast
// wave's p=1 prologue staging must not overwrite buffers a slow wave still
// reads in p=0's last tile). Heavy subproblem first.
__global__ __launch_bounds__(256, 4) void attn_kernel(const ushort_t* __restrict__ q,
                                                      const ushort_t* __restrict__ k,
                                                      const ushort_t* __restrict__ vt,
                                                      ushort_t* __restrict__ o) {
    int tid = threadIdx.x;
    int lane = tid & 63, w = tid >> 6;
    int c = lane & 15, quad = lane >> 4;
    int bh = blockIdx.x;
    int b = bh >> 4, h = bh & 15;
    int lr = lane >> 2, lq = lane & 3;
    const ushort_t* qb  = q + (size_t)b * 2048 * 1024 + h * 64;
    const ushort_t* kbp = k + (size_t)b * 2048 * 1024 + h * 64;
    const ushort_t* vtb = vt + (size_t)(b * 16 + h) * 64 * 2048;
    ushort_t* ob = o + (size_t)b * 2048 * 1024 + h * 64;

    __shared__ __align__(16) ushort_t Ks[2][8 * 512];   // 16 KB
    __shared__ __align__(16) ushort_t Vs[2][8 * 512];   // 16 KB
    __shared__ __align__(16) ushort_t Ps[64 * 64];      // 8 KB, XOR-swizzled

    const floatx4 zero = {0.f, 0.f, 0.f, 0.f};

    // P LDS addressing (shorts). Row = w*16 + c; row-bijective XOR (c&7)<<3.
    int pswz = (c & 7) << 3;
    int pwbase = ((w * 16 + c) * 64);                   // + nt*16 + quad*4, ^pswz
    int prbase = ((w * 16 + c) * 64);                   // + quad*8 (+32), ^pswz

    for (int pp = 0; pp < 2; pp++) {
        int qt = pp ? (int)blockIdx.y : 31 - (int)blockIdx.y;   // heavy first
        int t0w = qt * 64 + w * 16;
        int ntile = qt + 1;

        // Q rows for this subproblem; MFMA B operand (n=c -> q-row t0w+c).
        const ushort_t* qrow = qb + (size_t)(t0w + c) * 1024;
        short8 aq0 = *(const short8*)(qrow + quad * 8);
        short8 aq1 = *(const short8*)(qrow + 32 + quad * 8);

        float l_sum = 0.f;
        floatx4 oacc[4];
#pragma unroll
        for (int dt = 0; dt < 4; dt++) oacc[dt] = zero;

        short8 vf[8];                       // V(t) fragments, consumed at t+1
        short8 paA = {0,0,0,0,0,0,0,0};     // P(t) fragments, consumed at t+1
        short8 paB = {0,0,0,0,0,0,0,0};

        // prologue: stage tile 0 into buffer 0
#pragma unroll
        for (int ci = 0; ci < 4; ci++) {
            int ch = w * 4 + ci;
            if (ch < 8) {
                int nt = ch >> 1, hf = ch & 1;
                async16(kbp + (size_t)(nt * 16 + lr) * 1024 + hf * 32 + lq * 8,
                        Ks[0] + ch * 512);
            } else {
                int dt = (ch - 8) >> 1, hf = ch & 1;
                async16(vtb + (size_t)(dt * 16 + lr) * 2048 + hf * 32 + lq * 8,
                        Vs[0] + (ch - 8) * 512);
            }
        }

        for (int kt = 0; kt < ntile; kt++) {
            __syncthreads();    // drains tile kt's staging loads
            int cur = kt & 1;
            if (kt + 1 < ntile) {
                int s1 = (kt + 1) * 64;
                int nxt = cur ^ 1;
#pragma unroll
                for (int ci = 0; ci < 4; ci++) {
                    int ch = w * 4 + ci;
                    if (ch < 8) {
                        int nt = ch >> 1, hf = ch & 1;
                        async16(kbp + (size_t)(s1 + nt * 16 + lr) * 1024 + hf * 32 + lq * 8,
                                Ks[nxt] + ch * 512);
                    } else {
                        int dt = (ch - 8) >> 1, hf = ch & 1;
                        async16(vtb + (size_t)(dt * 16 + lr) * 2048 + s1 + hf * 32 + lq * 8,
                                Vs[nxt] + (ch - 8) * 512);
                    }
                }
            }
            int s0 = kt * 64;

            // ---- PV(kt-1): pure-register MFMAs — fill MFMA pipe while QK's
            // K ds_reads are in flight (wave-uniform guard)
            if (kt) {
                __builtin_amdgcn_s_setprio(1);
#pragma unroll
                for (int dt = 0; dt < 4; dt++) {
                    oacc[dt] = __builtin_amdgcn_mfma_f32_16x16x32_bf16(paA, vf[dt * 2], oacc[dt], 0, 0, 0);
                    oacc[dt] = __builtin_amdgcn_mfma_f32_16x16x32_bf16(paB, vf[dt * 2 + 1], oacc[dt], 0, 0, 0);
                }
                __builtin_amdgcn_s_setprio(0);
            }

            // ---- QK(kt) swapped: A = K rows (m=c -> s), B = Q regs (n=c -> t).
            floatx4 sacc[4];
#pragma unroll
            for (int nt = 0; nt < 4; nt++) sacc[nt] = zero;
            __builtin_amdgcn_s_setprio(1);
#pragma unroll
            for (int nt = 0; nt < 4; nt++) {
                short8 k0f = *(const short8*)(Ks[cur] + nt * 1024 + c * 32 + quad * 8);
                short8 k1f = *(const short8*)(Ks[cur] + nt * 1024 + 512 + c * 32 + quad * 8);
                sacc[nt] = __builtin_amdgcn_mfma_f32_16x16x32_bf16(k0f, aq0, sacc[nt], 0, 0, 0);
                sacc[nt] = __builtin_amdgcn_mfma_f32_16x16x32_bf16(k1f, aq1, sacc[nt], 0, 0, 0);
            }
            __builtin_amdgcn_s_setprio(0);

            // ---- V(kt) fragments -> regs (consumed at iter kt+1)
#pragma unroll
            for (int dt = 0; dt < 4; dt++) {
                vf[dt * 2]     = *(const short8*)(Vs[cur] + dt * 1024 + c * 32 + quad * 8);
                vf[dt * 2 + 1] = *(const short8*)(Vs[cur] + dt * 1024 + 512 + c * 32 + quad * 8);
            }

            // ---- SM(kt): bare v_exp_f32, pack, Ps write + pa readback
            if (kt == ntile - 1) {           // diagonal tile: causal mask
                int t = t0w + c;
#pragma unroll
                for (int nt = 0; nt < 4; nt++) {
                    short4v pk;
                    float pn = 0.f;
#pragma unroll
                    for (int r = 0; r < 4; r++) {
                        int s = s0 + nt * 16 + quad * 4 + r;
                        float e = ex2((s > t) ? NEG_BIG : sacc[nt][r]);
                        pn += e;
                        pk[r] = (short)f2bf_trunc(e);
                    }
                    l_sum += pn;
                    *(short4v*)(Ps + ((pwbase + nt * 16 + quad * 4) ^ pswz)) = pk;
                }
            } else {
#pragma unroll
                for (int nt = 0; nt < 4; nt++) {
                    short4v pk;
                    float pn = 0.f;
#pragma unroll
                    for (int r = 0; r < 4; r++) {
                        float e = ex2(sacc[nt][r]);
                        pn += e;
                        pk[r] = (short)f2bf_trunc(e);
                    }
                    l_sum += pn;
                    *(short4v*)(Ps + ((pwbase + nt * 16 + quad * 4) ^ pswz)) = pk;
                }
            }
            paA = *(const short8*)(Ps + ((prbase + quad * 8) ^ pswz));
            paB = *(const short8*)(Ps + ((prbase + 32 + quad * 8) ^ pswz));
        }

        // epilogue: PV for the final tile
        __builtin_amdgcn_s_setprio(1);
#pragma unroll
        for (int dt = 0; dt < 4; dt++) {
            oacc[dt] = __builtin_amdgcn_mfma_f32_16x16x32_bf16(paA, vf[dt * 2], oacc[dt], 0, 0, 0);
            oacc[dt] = __builtin_amdgcn_mfma_f32_16x16x32_bf16(paB, vf[dt * 2 + 1], oacc[dt], 0, 0, 0);
        }
        __builtin_amdgcn_s_setprio(0);

        // l reduce over quads; O write
        float l = l_sum;
        l += __shfl_xor(l, 16);
        l += __shfl_xor(l, 32);
        float linv0 = 1.0f / l;              // valid for row t0w + c
        float linv[4];
#pragma unroll
        for (int r = 0; r < 4; r++) linv[r] = __shfl(linv0, quad * 4 + r);

#pragma unroll
        for (int dt = 0; dt < 4; dt++)
#pragma unroll
            for (int r = 0; r < 4; r++) {
                int t = t0w + quad * 4 + r;
                ob[(size_t)t * 1024 + dt * 16 + c] = f2bf_trunc(oacc[dt][r] * linv[r]);
            }

        if (pp == 0) __syncthreads();   // Ks/Vs reuse guard before next prologue
    }
}

// ------------------------------------------------------------------ launch ---
extern "C" void kernel_launch(void* const* d_in, const int* in_sizes, int n_in,
                              void* d_out, int out_size, void* d_ws, size_t ws_size,
                              hipStream_t stream) {
    const ushort_t* x  = (const ushort_t*)d_in[0];
    const ushort_t* g  = (const ushort_t*)d_in[1];
    const ushort_t* Wq = (const ushort_t*)d_in[2];
    const ushort_t* Wk = (const ushort_t*)d_in[3];
    const ushort_t* Wv = (const ushort_t*)d_in[4];
    const ushort_t* Wo = (const ushort_t*)d_in[5];

    char* ws = (char*)d_ws;
    const size_t MB = 1ull << 20;
    ushort_t* xn   = (ushort_t*)(ws);            // 8 MB (reused as attn out)
    ushort_t* qb   = (ushort_t*)(ws + 8 * MB);   // 8 MB
    ushort_t* kb   = (ushort_t*)(ws + 16 * MB);  // 8 MB
    ushort_t* vt   = (ushort_t*)(ws + 24 * MB);  // 8 MB ([b,h,dh,s])
    ushort_t* WTq3 = (ushort_t*)(ws + 32 * MB);  // 6 MB (q|k|v transposed)
    ushort_t* WoT  = (ushort_t*)(ws + 38 * MB);  // 2 MB  -> total 40 MB
    ushort_t* at   = xn;

    prep_kernel<<<dim3(32, 32, 8), dim3(32, 8), 0, stream>>>(Wq, Wk, Wv, Wo, WTq3, WoT, x, g, xn);

    gemm_qkv<<<dim3(24, 32), 256, 0, stream>>>(xn, WTq3, qb, kb, vt);

    attn_kernel<<<dim3(32, 16), 256, 0, stream>>>(qb, kb, vt, at);

    gemm_out<<<dim3(16, 32), 256, 0, stream>>>(at, WoT, (float*)d_out);
}

// Round 15
// 176.070 us; speedup vs baseline: 1.0290x; 1.0290x over previous
//
#include <hip/hip_runtime.h>

typedef unsigned short ushort_t;
typedef __attribute__((ext_vector_type(8))) short short8;   // 8 bf16 (4 VGPRs)
typedef __attribute__((ext_vector_type(4))) short short4v;  // 4 bf16 (8 B)
typedef __attribute__((ext_vector_type(4))) float floatx4;  // 4 fp32 acc
typedef __attribute__((ext_vector_type(4))) unsigned uint4v;

#define DEV static __device__ __forceinline__
#define NEG_BIG (-1e30f)

typedef const __attribute__((address_space(1))) unsigned int* gas_ptr;
typedef __attribute__((address_space(3))) unsigned int* las_ptr;

// async global->LDS, 16B per lane; LDS dest = base + lane*16 (wave-uniform base)
DEV void async16(const ushort_t* g, ushort_t* l) {
    __builtin_amdgcn_global_load_lds((gas_ptr)(const void*)g, (las_ptr)(void*)l, 16, 0, 0);
}

// raw v_exp_f32: 2^x in ONE trans op (libm exp2f = ~10-op OCML path, R23;
// __expf = mul+exp, R19). Input pre-scaled by log2(e) in gemm_qkv.
DEV float ex2(float x) {
    float r;
    asm("v_exp_f32 %0, %1" : "=v"(r) : "v"(x));
    return r;
}

DEV float bf2f(ushort_t u) {
    union { unsigned u; float f; } v; v.u = ((unsigned)u) << 16; return v.f;
}
DEV ushort_t f2bf(float f) {            // RNE — for values feeding long chains
    union { float f; unsigned u; } v; v.f = f;
    unsigned r = v.u + 0x7FFF + ((v.u >> 16) & 1);
    return (ushort_t)(r >> 16);
}
DEV ushort_t f2bf_trunc(float f) {      // 1-op truncation — P / O only (R13)
    union { float f; unsigned u; } v; v.f = f;
    return (ushort_t)(v.u >> 16);
}
DEV float scrub_f32_bits(unsigned u) {  // inf/nan -> 0
    if (((u >> 23) & 0xFF) == 0xFF) u = 0;
    union { unsigned u; float f; } v; v.u = u; return v.f;
}
DEV float scrub_bf16_bits(ushort_t u) {
    if (((u >> 7) & 0xFF) == 0xFF) u = 0;
    return bf2f(u);
}

// Probe: fp32 vs bf16 raw data (proven in R3/R4). Block-uniform result.
DEV int probe_is_f32(const ushort_t* __restrict__ p) {
    int tid = threadIdx.x + threadIdx.y * blockDim.x;
    int nthr = blockDim.x * blockDim.y;
    __shared__ int cnt;
    if (tid == 0) cnt = 0;
    __syncthreads();
    int weird = 0;
    for (int i = tid; i < 2048; i += nthr) {
        unsigned e = (p[i] >> 7) & 0xFF;
        weird += (e >= 0x90) ? 1 : 0;
    }
#pragma unroll
    for (int off = 32; off; off >>= 1) weird += __shfl_xor(weird, off);
    if ((tid & 63) == 0) atomicAdd(&cnt, weird);
    __syncthreads();
    return cnt > 16;
}

// ----------------------------------------------- fused prep (1 launch) ------
// R26 (verified): G13-vectorized transpose + RMSNorm. Per-element arithmetic
// identical to scalar version (same scrub, same f2bf RNE).
__global__ void prep_kernel(const ushort_t* __restrict__ W0,
                            const ushort_t* __restrict__ W1,
                            const ushort_t* __restrict__ W2,
                            const ushort_t* __restrict__ W3,
                            ushort_t* __restrict__ WTq3,
                            ushort_t* __restrict__ WoT,
                            const ushort_t* __restrict__ x,
                            const ushort_t* __restrict__ g,
                            ushort_t* __restrict__ xn) {
    int is_f32 = probe_is_f32(x);
    int z = blockIdx.z;
    int tid = threadIdx.y * 32 + threadIdx.x;
    if (z < 4) {
        const ushort_t* W = (z == 0) ? W0 : (z == 1) ? W1 : (z == 2) ? W2 : W3;
        __shared__ ushort_t tile[32][36];   // row stride 36 shorts = 72 B
        int kk = tid >> 3;                  // 0..31  (k-local)
        int nl = (tid & 7) * 4;             // 0,4,..,28 (n-local)
        size_t src = (size_t)(blockIdx.y * 32 + kk) * 1024 + blockIdx.x * 32 + nl;
        short4v tv;
        if (is_f32) {
            uint4v u = *(const uint4v*)((const unsigned*)W + src);
#pragma unroll
            for (int i = 0; i < 4; i++) tv[i] = (short)f2bf(scrub_f32_bits(u[i]));
        } else {
            short4v u = *(const short4v*)(W + src);
#pragma unroll
            for (int i = 0; i < 4; i++) tv[i] = (short)f2bf(scrub_bf16_bits((ushort_t)u[i]));
        }
        *(short4v*)(&tile[kk][nl]) = tv;
        __syncthreads();
        int nn = tid >> 3;                  // n-local
        int kl = (tid & 7) * 4;             // k-local
        ushort_t* dst = (z < 3) ? WTq3 : WoT;
        int ny = blockIdx.x * 32 + ((z < 3) ? z * 1024 : 0) + nn;
        short4v ov;
#pragma unroll
        for (int i = 0; i < 4; i++) ov[i] = tile[kl + i][nn];
        *(short4v*)(dst + (size_t)ny * 1024 + blockIdx.y * 32 + kl) = ov;
    } else {
        int row = (z - 4) * 1024 + blockIdx.y * 32 + blockIdx.x;
        float vals[4], gv[4];
        size_t base = (size_t)row * 1024 + tid * 4;
        if (is_f32) {
            uint4v xv = *(const uint4v*)((const unsigned*)x + base);
            uint4v gvv = *(const uint4v*)((const unsigned*)g + tid * 4);
#pragma unroll
            for (int i = 0; i < 4; i++) {
                vals[i] = scrub_f32_bits(xv[i]);
                gv[i]   = scrub_f32_bits(gvv[i]);
            }
        } else {
            short4v xv = *(const short4v*)(x + base);
            short4v gvv = *(const short4v*)(g + tid * 4);
#pragma unroll
            for (int i = 0; i < 4; i++) {
                vals[i] = scrub_bf16_bits((ushort_t)xv[i]);
                gv[i]   = scrub_bf16_bits((ushort_t)gvv[i]);
            }
        }
        float ss = vals[0]*vals[0] + vals[1]*vals[1] + vals[2]*vals[2] + vals[3]*vals[3];
#pragma unroll
        for (int off = 32; off > 0; off >>= 1) ss += __shfl_xor(ss, off);
        __shared__ float red[4];
        if ((tid & 63) == 0) red[tid >> 6] = ss;
        __syncthreads();
        ss = red[0] + red[1] + red[2] + red[3];
        float inv = rsqrtf(ss * (1.0f / 1024.0f) + 1e-6f);
        short4v ov;
#pragma unroll
        for (int i = 0; i < 4; i++) ov[i] = (short)f2bf(vals[i] * inv * gv[i]);
        *(short4v*)(xn + base) = ov;
    }
}

// ------------------------------------------------------- fused QKV GEMM ----
// 128x128 tile, BK=64, COALESCED async staging (R8/R10-verified; R9 proved
// bank conflicts benign / coalescing binding). XCD-region swizzle.
// Epilogue: fast-math RoPE (__sinf/__cosf), packed V scatter.
// q pre-scale = 0.125 * log2(e): attn softmax uses raw v_exp_f32 (2^x).
__global__ __launch_bounds__(256, 4) void gemm_qkv(const ushort_t* __restrict__ A,
                                                   const ushort_t* __restrict__ Bt,
                                                   ushort_t* __restrict__ qb,
                                                   ushort_t* __restrict__ kb,
                                                   ushort_t* __restrict__ vt) {
    const int K = 1024;
    int tid = threadIdx.x;
    int lane = tid & 63, w = tid >> 6;
    int c = lane & 15, quad = lane >> 4;
    int mh = w >> 1, nh = w & 1;
    int lin = blockIdx.y * gridDim.x + blockIdx.x;     // 768 blocks
    int xcd = lin & 7, idx = lin >> 3;
    int bm = ((xcd & 3) * 8 + (idx & 7)) * 128;        // m-block in [0,32)
    int bn = ((xcd >> 2) * 12 + (idx >> 3)) * 128;     // n-block in [0,24)
    int lr = lane >> 2, lq = lane & 3;                 // staging lane map

    __shared__ __align__(16) ushort_t As[16 * 512];    // 16 KB
    __shared__ __align__(16) ushort_t Bs[16 * 512];    // 16 KB

    const floatx4 zero = {0.f, 0.f, 0.f, 0.f};
    floatx4 acc[4][4];
#pragma unroll
    for (int i = 0; i < 4; i++)
#pragma unroll
        for (int j = 0; j < 4; j++) acc[i][j] = zero;

    for (int k0 = 0; k0 < K; k0 += 64) {
        __syncthreads();
#pragma unroll
        for (int ci = 0; ci < 8; ci++) {
            int ch = w * 8 + ci;              // 0..31, wave-uniform
            if (ch < 16) {
                int rg = ch >> 1, kc = ch & 1;
                async16(A + (size_t)(bm + rg * 16 + lr) * K + k0 + kc * 32 + lq * 8,
                        As + ch * 512);
            } else {
                int b2 = ch - 16;
                int rg = b2 >> 1, kc = b2 & 1;
                async16(Bt + (size_t)(bn + rg * 16 + lr) * K + k0 + kc * 32 + lq * 8,
                        Bs + b2 * 512);
            }
        }
        __syncthreads();
#pragma unroll
        for (int kc = 0; kc < 2; kc++) {
            short8 af[4], bf[4];
#pragma unroll
            for (int i = 0; i < 4; i++)
                af[i] = *(const short8*)(As + ((mh * 4 + i) * 2 + kc) * 512 + c * 32 + quad * 8);
#pragma unroll
            for (int j = 0; j < 4; j++)
                bf[j] = *(const short8*)(Bs + ((nh * 4 + j) * 2 + kc) * 512 + c * 32 + quad * 8);
#pragma unroll
            for (int i = 0; i < 4; i++)
#pragma unroll
                for (int j = 0; j < 4; j++)
                    acc[i][j] = __builtin_amdgcn_mfma_f32_16x16x32_bf16(af[i], bf[j], acc[i][j], 0, 0, 0);
        }
    }

    int proj = bn >> 10;                 // 0=q, 1=k, 2=v (blocks never straddle)
    int n0 = (bn & 1023) + nh * 64;
    if (proj < 2) {                      // RoPE: d = j*16+c, pairs (j, j+2)
        float th0 = exp2f((float)c * (-19.931568569324174f / 32.0f));
        float th1 = exp2f((float)(16 + c) * (-19.931568569324174f / 32.0f));
        // q scale folds 1/sqrt(dh)=0.125 AND log2(e) so attn uses exp2 directly
        float scale = (proj == 0) ? 0.125f * 1.4426950408889634f : 1.0f;
#pragma unroll
        for (int i = 0; i < 4; i++)
#pragma unroll
            for (int r = 0; r < 4; r++) {
                int s = (bm + mh * 64 + i * 16 + quad * 4 + r) & 2047;
                float a0 = (float)s * th0, a1 = (float)s * th1;
                float sn0 = __sinf(a0), cs0 = __cosf(a0);
                float sn1 = __sinf(a1), cs1 = __cosf(a1);
                float x1a = acc[i][0][r], x2a = acc[i][2][r];
                acc[i][0][r] = (x1a * cs0 - x2a * sn0) * scale;
                acc[i][2][r] = (x1a * sn0 + x2a * cs0) * scale;
                float x1b = acc[i][1][r], x2b = acc[i][3][r];
                acc[i][1][r] = (x1b * cs1 - x2b * sn1) * scale;
                acc[i][3][r] = (x1b * sn1 + x2b * cs1) * scale;
            }
        ushort_t* dst = (proj == 0) ? qb : kb;
#pragma unroll
        for (int i = 0; i < 4; i++)
#pragma unroll
            for (int j = 0; j < 4; j++)
#pragma unroll
                for (int r = 0; r < 4; r++) {
                    int row = bm + mh * 64 + i * 16 + quad * 4 + r;
                    dst[(size_t)row * 1024 + n0 + j * 16 + c] = f2bf(acc[i][j][r]);
                }
    } else {                             // V: packed 8-B scatter (4 consecutive s)
#pragma unroll
        for (int i = 0; i < 4; i++) {
            int row0 = bm + mh * 64 + i * 16 + quad * 4;
            int b = row0 >> 11, s0v = row0 & 2047;
#pragma unroll
            for (int j = 0; j < 4; j++) {
                int col = n0 + j * 16 + c;
                int hh = col >> 6, dh = col & 63;
                short4v pk;
#pragma unroll
                for (int r = 0; r < 4; r++) pk[r] = (short)f2bf(acc[i][j][r]);
                *(short4v*)(vt + (size_t)((b * 16 + hh) * 64 + dh) * 2048 + s0v) = pk;
            }
        }
    }
}

// ----------------------------------------------------- output projection ---
__global__ __launch_bounds__(256, 4) void gemm_out(const ushort_t* __restrict__ A,
                                                   const ushort_t* __restrict__ Bt,
                                                   float* __restrict__ C) {
    const int K = 1024, N = 1024;
    int tid = threadIdx.x;
    int lane = tid & 63, w = tid >> 6;
    int c = lane & 15, quad = lane >> 4;
    int mh = w >> 1, nh = w & 1;
    int lin = blockIdx.y * gridDim.x + blockIdx.x;     // 512 blocks
    int xcd = lin & 7, idx = lin >> 3;
    int bm = ((xcd & 3) * 8 + (idx & 7)) * 128;
    int bn = ((xcd >> 2) * 8 + (idx >> 3)) * 64;
    int lr = lane >> 2, lq = lane & 3;

    __shared__ __align__(16) ushort_t As[16 * 512];
    __shared__ __align__(16) ushort_t Bs[8 * 512];

    const floatx4 zero = {0.f, 0.f, 0.f, 0.f};
    floatx4 acc[4][2];
#pragma unroll
    for (int i = 0; i < 4; i++)
#pragma unroll
        for (int j = 0; j < 2; j++) acc[i][j] = zero;

    for (int k0 = 0; k0 < K; k0 += 64) {
        __syncthreads();
#pragma unroll
        for (int ci = 0; ci < 6; ci++) {
            int ch = w * 6 + ci;              // 0..23, wave-uniform
            if (ch < 16) {
                int rg = ch >> 1, kc = ch & 1;
                async16(A + (size_t)(bm + rg * 16 + lr) * K + k0 + kc * 32 + lq * 8,
                        As + ch * 512);
            } else {
                int b2 = ch - 16;
                int rg = b2 >> 1, kc = b2 & 1;
                async16(Bt + (size_t)(bn + rg * 16 + lr) * K + k0 + kc * 32 + lq * 8,
                        Bs + b2 * 512);
            }
        }
        __syncthreads();
#pragma unroll
        for (int kc = 0; kc < 2; kc++) {
            short8 af[4], bf[2];
#pragma unroll
            for (int i = 0; i < 4; i++)
                af[i] = *(const short8*)(As + ((mh * 4 + i) * 2 + kc) * 512 + c * 32 + quad * 8);
#pragma unroll
            for (int j = 0; j < 2; j++)
                bf[j] = *(const short8*)(Bs + ((nh * 2 + j) * 2 + kc) * 512 + c * 32 + quad * 8);
#pragma unroll
            for (int i = 0; i < 4; i++)
#pragma unroll
                for (int j = 0; j < 2; j++)
                    acc[i][j] = __builtin_amdgcn_mfma_f32_16x16x32_bf16(af[i], bf[j], acc[i][j], 0, 0, 0);
        }
    }
#pragma unroll
    for (int i = 0; i < 4; i++)
#pragma unroll
        for (int j = 0; j < 2; j++)
#pragma unroll
            for (int r = 0; r < 4; r++) {
                int row = bm + mh * 64 + i * 16 + quad * 4 + r;
                int col = bn + nh * 32 + j * 16 + c;
                C[(size_t)row * N + col] = acc[i][j][r];
            }
}

// -------------------------------------------------------------- attention ---
// R28 = R26/R25-verbatim (session best, 179.0 µs total): cross-tile PV
// pipeline — PV(t-1) runs first each iter as pure-register MFMAs (pa/vf
// carried), filling the MFMA pipe while QK(t)'s K ds_reads are in flight.
// Swapped QK^T, b64-P-write/b128-read XOR-swizzled Ps, bare v_exp_f32
// softmax (log2e folded into q), setprio on MFMA clusters, K/V dbuf staging
// via global_load_lds, LDS 40960 B = 4 blocks/CU, grid (32,32).
// Imbalance theory CLOSED: R20 (remap) null, R27 (paired tiles, 2/CU) −12%
// — concurrency from 4 blocks/CU outweighs tail imbalance.
__global__ __launch_bounds__(256, 4) void attn_kernel(const ushort_t* __restrict__ q,
                                                      const ushort_t* __restrict__ k,
                                                      const ushort_t* __restrict__ vt,
                                                      ushort_t* __restrict__ o) {
    int tid = threadIdx.x;
    int lane = tid & 63, w = tid >> 6;
    int c = lane & 15, quad = lane >> 4;
    int bh = blockIdx.x;
    int b = bh >> 4, h = bh & 15;
    int qt = 31 - (int)blockIdx.y;      // heaviest (qt=31) first
    int lr = lane >> 2, lq = lane & 3;
    const ushort_t* qb  = q + (size_t)b * 2048 * 1024 + h * 64;
    const ushort_t* kbp = k + (size_t)b * 2048 * 1024 + h * 64;
    const ushort_t* vtb = vt + (size_t)(b * 16 + h) * 64 * 2048;
    ushort_t* ob = o + (size_t)b * 2048 * 1024 + h * 64;

    __shared__ __align__(16) ushort_t Ks[2][8 * 512];   // 16 KB
    __shared__ __align__(16) ushort_t Vs[2][8 * 512];   // 16 KB
    __shared__ __align__(16) ushort_t Ps[64 * 64];      // 8 KB, XOR-swizzled

    const floatx4 zero = {0.f, 0.f, 0.f, 0.f};

    int t0b = qt * 64;
    int t0w = t0b + w * 16;
    int ntile = qt + 1;

    // Q rows for this wave; MFMA B operand (n=lane&15=c -> q-row t0w+c).
    const ushort_t* qrow = qb + (size_t)(t0w + c) * 1024;
    short8 aq0 = *(const short8*)(qrow + quad * 8);
    short8 aq1 = *(const short8*)(qrow + 32 + quad * 8);

    // P LDS addressing (shorts). Row = w*16 + c; row-bijective XOR (c&7)<<3.
    int pswz = (c & 7) << 3;
    int pwbase = ((w * 16 + c) * 64);                   // + nt*16 + quad*4, ^pswz
    int prbase = ((w * 16 + c) * 64);                   // + quad*8 (+32), ^pswz

    float l_sum = 0.f;
    floatx4 oacc[4];
#pragma unroll
    for (int dt = 0; dt < 4; dt++) oacc[dt] = zero;

    short8 vf[8];                       // V(t) fragments, consumed at t+1
    short8 paA = {0,0,0,0,0,0,0,0};     // P(t) fragments, consumed at t+1
    short8 paB = {0,0,0,0,0,0,0,0};

    // prologue: stage tile 0 into buffer 0
#pragma unroll
    for (int ci = 0; ci < 4; ci++) {
        int ch = w * 4 + ci;
        if (ch < 8) {
            int nt = ch >> 1, hf = ch & 1;
            async16(kbp + (size_t)(nt * 16 + lr) * 1024 + hf * 32 + lq * 8,
                    Ks[0] + ch * 512);
        } else {
            int dt = (ch - 8) >> 1, hf = ch & 1;
            async16(vtb + (size_t)(dt * 16 + lr) * 2048 + hf * 32 + lq * 8,
                    Vs[0] + (ch - 8) * 512);
        }
    }

    for (int kt = 0; kt < ntile; kt++) {
        __syncthreads();    // drains tile kt's staging loads
        int cur = kt & 1;
        if (kt + 1 < ntile) {
            int s1 = (kt + 1) * 64;
            int nxt = cur ^ 1;
#pragma unroll
            for (int ci = 0; ci < 4; ci++) {
                int ch = w * 4 + ci;
                if (ch < 8) {
                    int nt = ch >> 1, hf = ch & 1;
                    async16(kbp + (size_t)(s1 + nt * 16 + lr) * 1024 + hf * 32 + lq * 8,
                            Ks[nxt] + ch * 512);
                } else {
                    int dt = (ch - 8) >> 1, hf = ch & 1;
                    async16(vtb + (size_t)(dt * 16 + lr) * 2048 + s1 + hf * 32 + lq * 8,
                            Vs[nxt] + (ch - 8) * 512);
                }
            }
        }
        int s0 = kt * 64;

        // ---- PV(kt-1): pure-register MFMAs — fill MFMA pipe while QK's
        // K ds_reads are in flight (wave-uniform guard)
        if (kt) {
            __builtin_amdgcn_s_setprio(1);
#pragma unroll
            for (int dt = 0; dt < 4; dt++) {
                oacc[dt] = __builtin_amdgcn_mfma_f32_16x16x32_bf16(paA, vf[dt * 2], oacc[dt], 0, 0, 0);
                oacc[dt] = __builtin_amdgcn_mfma_f32_16x16x32_bf16(paB, vf[dt * 2 + 1], oacc[dt], 0, 0, 0);
            }
            __builtin_amdgcn_s_setprio(0);
        }

        // ---- QK(kt) swapped: A = K rows (m=c -> s), B = Q regs (n=c -> t).
        // sacc[nt][r] = S[t0w + c][s0 + nt*16 + quad*4 + r] (pre-scaled log2e)
        floatx4 sacc[4];
#pragma unroll
        for (int nt = 0; nt < 4; nt++) sacc[nt] = zero;
        __builtin_amdgcn_s_setprio(1);
#pragma unroll
        for (int nt = 0; nt < 4; nt++) {
            short8 k0f = *(const short8*)(Ks[cur] + nt * 1024 + c * 32 + quad * 8);
            short8 k1f = *(const short8*)(Ks[cur] + nt * 1024 + 512 + c * 32 + quad * 8);
            sacc[nt] = __builtin_amdgcn_mfma_f32_16x16x32_bf16(k0f, aq0, sacc[nt], 0, 0, 0);
            sacc[nt] = __builtin_amdgcn_mfma_f32_16x16x32_bf16(k1f, aq1, sacc[nt], 0, 0, 0);
        }
        __builtin_amdgcn_s_setprio(0);

        // ---- V(kt) fragments -> regs (consumed at iter kt+1; huge slack)
#pragma unroll
        for (int dt = 0; dt < 4; dt++) {
            vf[dt * 2]     = *(const short8*)(Vs[cur] + dt * 1024 + c * 32 + quad * 8);
            vf[dt * 2 + 1] = *(const short8*)(Vs[cur] + dt * 1024 + 512 + c * 32 + quad * 8);
        }

        // ---- SM(kt): exp2 via bare v_exp_f32, pack, Ps write + pa readback
        // (write->read latency hides behind loop-back barrier + staging)
        if (kt == ntile - 1) {           // diagonal tile: causal mask
            int t = t0w + c;
#pragma unroll
            for (int nt = 0; nt < 4; nt++) {
                short4v pk;
                float pn = 0.f;
#pragma unroll
                for (int r = 0; r < 4; r++) {
                    int s = s0 + nt * 16 + quad * 4 + r;
                    float e = ex2((s > t) ? NEG_BIG : sacc[nt][r]);
                    pn += e;
                    pk[r] = (short)f2bf_trunc(e);
                }
                l_sum += pn;
                *(short4v*)(Ps + ((pwbase + nt * 16 + quad * 4) ^ pswz)) = pk;
            }
        } else {
#pragma unroll
            for (int nt = 0; nt < 4; nt++) {
                short4v pk;
                float pn = 0.f;
#pragma unroll
                for (int r = 0; r < 4; r++) {
                    float e = ex2(sacc[nt][r]);
                    pn += e;
                    pk[r] = (short)f2bf_trunc(e);
                }
                l_sum += pn;
                *(short4v*)(Ps + ((pwbase + nt * 16 + quad * 4) ^ pswz)) = pk;
            }
        }
        paA = *(const short8*)(Ps + ((prbase + quad * 8) ^ pswz));
        paB = *(const short8*)(Ps + ((prbase + 32 + quad * 8) ^ pswz));
    }

    // epilogue: PV for the final tile
    __builtin_amdgcn_s_setprio(1);
#pragma unroll
    for (int dt = 0; dt < 4; dt++) {
        oacc[dt] = __builtin_amdgcn_mfma_f32_16x16x32_bf16(paA, vf[dt * 2], oacc[dt], 0, 0, 0);
        oacc[dt] = __builtin_amdgcn_mfma_f32_16x16x32_bf16(paB, vf[dt * 2 + 1], oacc[dt], 0, 0, 0);
    }
    __builtin_amdgcn_s_setprio(0);

    // l_sum is the quad-partial row sum for q-row t0w + c -> reduce over quads
    float l = l_sum;
    l += __shfl_xor(l, 16);
    l += __shfl_xor(l, 32);
    float linv0 = 1.0f / l;              // valid for row t0w + c
    float linv[4];
#pragma unroll
    for (int r = 0; r < 4; r++) linv[r] = __shfl(linv0, quad * 4 + r);

#pragma unroll
    for (int dt = 0; dt < 4; dt++)
#pragma unroll
        for (int r = 0; r < 4; r++) {
            int t = t0w + quad * 4 + r;
            ob[(size_t)t * 1024 + dt * 16 + c] = f2bf_trunc(oacc[dt][r] * linv[r]);
        }
}

// ------------------------------------------------------------------ launch ---
extern "C" void kernel_launch(void* const* d_in, const int* in_sizes, int n_in,
                              void* d_out, int out_size, void* d_ws, size_t ws_size,
                              hipStream_t stream) {
    const ushort_t* x  = (const ushort_t*)d_in[0];
    const ushort_t* g  = (const ushort_t*)d_in[1];
    const ushort_t* Wq = (const ushort_t*)d_in[2];
    const ushort_t* Wk = (const ushort_t*)d_in[3];
    const ushort_t* Wv = (const ushort_t*)d_in[4];
    const ushort_t* Wo = (const ushort_t*)d_in[5];

    char* ws = (char*)d_ws;
    const size_t MB = 1ull << 20;
    ushort_t* xn   = (ushort_t*)(ws);            // 8 MB (reused as attn out)
    ushort_t* qb   = (ushort_t*)(ws + 8 * MB);   // 8 MB
    ushort_t* kb   = (ushort_t*)(ws + 16 * MB);  // 8 MB
    ushort_t* vt   = (ushort_t*)(ws + 24 * MB);  // 8 MB ([b,h,dh,s])
    ushort_t* WTq3 = (ushort_t*)(ws + 32 * MB);  // 6 MB (q|k|v transposed)
    ushort_t* WoT  = (ushort_t*)(ws + 38 * MB);  // 2 MB  -> total 40 MB
    ushort_t* at   = xn;

    prep_kernel<<<dim3(32, 32, 8), dim3(32, 8), 0, stream>>>(Wq, Wk, Wv, Wo, WTq3, WoT, x, g, xn);

    gemm_qkv<<<dim3(24, 32), 256, 0, stream>>>(xn, WTq3, qb, kb, vt);

    attn_kernel<<<dim3(32, 32), 256, 0, stream>>>(qb, kb, vt, at);

    gemm_out<<<dim3(16, 32), 256, 0, stream>>>(at, WoT, (float*)d_out);
}